// Round 10
// baseline (1770.193 us; speedup 1.0000x reference)
//
#include <hip/hip_runtime.h>
#include <hip/hip_cooperative_groups.h>

namespace cg = cooperative_groups;

#define I_DIM 2304
#define J_DIM 32
#define D_IN  8
#define E_DIM 16
#define B_DIM 64
#define BJE   32768                    // B*J*E
#define NCF   256                      // i-chunks == grid size
#define CHF   9                        // i's per chunk
#define TILEW 4096                     // floats per 16KB W tile

typedef const __attribute__((address_space(1))) char* gcp_t;
typedef __attribute__((address_space(3)))       char* lcp_t;

// ONE cooperative kernel: grid=256 blocks (1/CU, LDS-capped), 512 thr = 8 waves.
// Prologue: DMA all 9 W tiles of this block's i-chunk to LDS ONCE (source-XOR-
// swizzled, linear dest — v7/v9-proven), stage b0. Then 3 routing passes
// in-kernel, grid.sync() between compute/reduce phases.
// Wave wv owns b = wv*8 + bb; processed as 4 sequential PAIRS (bh-split) so the
// live register set stays ~85 (vacc[2][8]+Sacc[2][8]+uh[2][8]+temps) — under
// the empirical 128-VGPR cap hipcc gives 512-thr blocks -> no scratch.
// Lane: jj = j, eh = e-half. x read as wave-uniform float4 vector loads
// (L1-hot broadcast; NOT scalar s_load — v6 lesson).
__global__ __launch_bounds__(512, 2) void caps_fused(
    const float* __restrict__ x,       // [B, I, 8]
    const float* __restrict__ W,       // [I, J, 8, 16]
    const float* __restrict__ b0,      // [I, J]
    float* __restrict__ VaccBuf,       // [B*J*E] running sum of V (ws)
    float* __restrict__ partial,       // [NCF][B*J*E] (ws)
    float* __restrict__ out)           // [B*J*E]
{
    cg::grid_group grid = cg::this_grid();
    const int tid   = threadIdx.x;
    const int wv    = __builtin_amdgcn_readfirstlane(tid >> 6);  // 0..7 (SGPR)
    const int lane  = tid & 63;
    const int jj    = lane & 31;
    const int eh    = lane >> 5;
    const int km    = jj & 15;
    const int chunk = blockIdx.x;      // 0..255
    const int i0    = chunk * CHF;
    const int bw0   = wv * 8;

    __shared__ float Ws[CHF * TILEW];  // 147,456 B
    __shared__ float B0s[CHF * J_DIM]; // 1,152 B
    __shared__ float Red[512];         // 2,048 B   -> 150.6 KB total

    // ---- prologue: DMA all 9 W tiles (1024 16B-units each; 2 per thread) ----
#pragma unroll
    for (int r = 0; r < 2; ++r) {
        const int g    = r * 512 + tid;                             // unit 0..1023
        const int srcu = (g & ~31) | ((g & 31) ^ ((g >> 5) & 15));  // swizzled src
        for (int t = 0; t < CHF; ++t) {
            const char* wt = (const char*)(W + (size_t)(i0 + t) * TILEW);
            __builtin_amdgcn_global_load_lds(
                (gcp_t)(wt + (size_t)srcu * 16),
                (lcp_t)((char*)&Ws[t * TILEW + g * 4]),
                16, 0, 0);
        }
    }
    if (tid < CHF * J_DIM) B0s[tid] = b0[i0 * J_DIM + tid];
    __syncthreads();   // drains DMA; W resident for the entire kernel

#pragma unroll 1
    for (int pass = 0; pass < 3; ++pass) {
        // ================= compute phase: partial S for this chunk =================
#pragma unroll 1
        for (int bh = 0; bh < 4; ++bh) {
            const int bA = bw0 + bh * 2;     // pair of b's: bA, bA+1

            float vacc[2][8];
            if (pass == 0) {
#pragma unroll
                for (int bl = 0; bl < 2; ++bl)
#pragma unroll
                    for (int e = 0; e < 8; ++e) vacc[bl][e] = 0.f;
            } else {
#pragma unroll
                for (int bl = 0; bl < 2; ++bl) {
                    const float* vp = VaccBuf + ((bA + bl) * 512 + jj * 16 + eh * 8);
                    const float4 v0 = *(const float4*)vp;
                    const float4 v1 = *(const float4*)(vp + 4);
                    vacc[bl][0]=v0.x; vacc[bl][1]=v0.y; vacc[bl][2]=v0.z; vacc[bl][3]=v0.w;
                    vacc[bl][4]=v1.x; vacc[bl][5]=v1.y; vacc[bl][6]=v1.z; vacc[bl][7]=v1.w;
                }
            }

            float Sacc[2][8];
#pragma unroll
            for (int bl = 0; bl < 2; ++bl)
#pragma unroll
                for (int e = 0; e < 8; ++e) Sacc[bl][e] = 0.f;

#pragma unroll
            for (int ii = 0; ii < CHF; ++ii) {
                const int i = i0 + ii;
                const float* wb = &Ws[ii * TILEW];

                // x for the 2 b's: wave-uniform float4 vector loads (broadcast)
                float xA[8], xB[8];
                {
                    const float* xpA = x + ((size_t)bA * I_DIM + i) * D_IN;
                    const float4 a0 = *(const float4*)xpA;
                    const float4 a1 = *(const float4*)(xpA + 4);
                    const float* xpB = xpA + (size_t)I_DIM * D_IN;
                    const float4 c0 = *(const float4*)xpB;
                    const float4 c1 = *(const float4*)(xpB + 4);
                    xA[0]=a0.x; xA[1]=a0.y; xA[2]=a0.z; xA[3]=a0.w;
                    xA[4]=a1.x; xA[5]=a1.y; xA[6]=a1.z; xA[7]=a1.w;
                    xB[0]=c0.x; xB[1]=c0.y; xB[2]=c0.z; xB[3]=c0.w;
                    xB[4]=c1.x; xB[5]=c1.y; xB[6]=c1.z; xB[7]=c1.w;
                }

                float uh[2][8];
#pragma unroll
                for (int bl = 0; bl < 2; ++bl)
#pragma unroll
                    for (int e = 0; e < 8; ++e) uh[bl][e] = 0.f;

#pragma unroll
                for (int d = 0; d < D_IN; ++d) {
                    const int u0 = (d << 2) | (eh << 1);
                    const float4 wlo = *(const float4*)&wb[jj * 128 + (((u0    ) ^ km) << 2)];
                    const float4 whi = *(const float4*)&wb[jj * 128 + (((u0 | 1) ^ km) << 2)];
                    const float xa = xA[d], xb = xB[d];
                    uh[0][0] = fmaf(xa, wlo.x, uh[0][0]);
                    uh[0][1] = fmaf(xa, wlo.y, uh[0][1]);
                    uh[0][2] = fmaf(xa, wlo.z, uh[0][2]);
                    uh[0][3] = fmaf(xa, wlo.w, uh[0][3]);
                    uh[0][4] = fmaf(xa, whi.x, uh[0][4]);
                    uh[0][5] = fmaf(xa, whi.y, uh[0][5]);
                    uh[0][6] = fmaf(xa, whi.z, uh[0][6]);
                    uh[0][7] = fmaf(xa, whi.w, uh[0][7]);
                    uh[1][0] = fmaf(xb, wlo.x, uh[1][0]);
                    uh[1][1] = fmaf(xb, wlo.y, uh[1][1]);
                    uh[1][2] = fmaf(xb, wlo.z, uh[1][2]);
                    uh[1][3] = fmaf(xb, wlo.w, uh[1][3]);
                    uh[1][4] = fmaf(xb, whi.x, uh[1][4]);
                    uh[1][5] = fmaf(xb, whi.y, uh[1][5]);
                    uh[1][6] = fmaf(xb, whi.z, uh[1][6]);
                    uh[1][7] = fmaf(xb, whi.w, uh[1][7]);
                }

                const float b0v = B0s[ii * J_DIM + jj];
#pragma unroll
                for (int bl = 0; bl < 2; ++bl) {
                    float l0 = 0.f, l1 = 0.f;
#pragma unroll
                    for (int e = 0; e < 8; e += 2) {
                        l0 = fmaf(vacc[bl][e],     uh[bl][e],     l0);
                        l1 = fmaf(vacc[bl][e + 1], uh[bl][e + 1], l1);
                    }
                    float lg = l0 + l1;
                    lg += __shfl_xor(lg, 32);            // other e-half
                    const float l = b0v + lg;

                    // softmax over jj (no max-sub: |logit| small, fp32-safe)
                    const float p = __expf(l);
                    float s = p;
#pragma unroll
                    for (int k = 16; k >= 1; k >>= 1) s += __shfl_xor(s, k);
                    const float c = p * __builtin_amdgcn_rcpf(s);

#pragma unroll
                    for (int e = 0; e < 8; ++e)
                        Sacc[bl][e] = fmaf(c, uh[bl][e], Sacc[bl][e]);
                }
            }

#pragma unroll
            for (int bl = 0; bl < 2; ++bl) {
                float* pp = partial + (size_t)chunk * BJE
                          + ((bA + bl) * 512 + jj * 16 + eh * 8);
                *(float4*)pp       = make_float4(Sacc[bl][0], Sacc[bl][1], Sacc[bl][2], Sacc[bl][3]);
                *(float4*)(pp + 4) = make_float4(Sacc[bl][4], Sacc[bl][5], Sacc[bl][6], Sacc[bl][7]);
            }
        }

        __threadfence();
        grid.sync();   // all partials visible device-wide

        // ================= reduce + squash: block owns 128 elems =================
        {
            const int eidx = blockIdx.x * 128 + (tid & 127);   // 0..BJE-1
            const int cq   = tid >> 7;                          // chunk-quarter 0..3
            float a0 = 0.f, a1 = 0.f, a2 = 0.f, a3 = 0.f;
            const int cbase = cq * 64;
            for (int c = 0; c < 64; c += 4) {
                a0 += partial[(size_t)(cbase + c + 0) * BJE + eidx];
                a1 += partial[(size_t)(cbase + c + 1) * BJE + eidx];
                a2 += partial[(size_t)(cbase + c + 2) * BJE + eidx];
                a3 += partial[(size_t)(cbase + c + 3) * BJE + eidx];
            }
            Red[tid] = (a0 + a1) + (a2 + a3);
            __syncthreads();
            if (tid < 128) {
                const float S = (Red[tid] + Red[tid + 128]) + (Red[tid + 256] + Red[tid + 384]);
                float s2 = S * S;
#pragma unroll
                for (int k = 8; k >= 1; k >>= 1) s2 += __shfl_xor(s2, k);  // over e
                const float scale = s2 / (1.f + s2) * rsqrtf(s2 + 1e-7f);
                const float v = scale * S;
                if (pass == 2)      out[eidx] = v;
                else if (pass == 0) VaccBuf[eidx] = v;
                else                VaccBuf[eidx] = VaccBuf[eidx] + v;
            }
            __syncthreads();
        }

        if (pass < 2) { __threadfence(); grid.sync(); }  // Vacc visible for next pass
    }
}

extern "C" void kernel_launch(void* const* d_in, const int* in_sizes, int n_in,
                              void* d_out, int out_size, void* d_ws, size_t ws_size,
                              hipStream_t stream) {
    const float* x  = (const float*)d_in[0];   // [64,2304,8]
    const float* W  = (const float*)d_in[1];   // [2304,32,8,16]
    const float* b0 = (const float*)d_in[2];   // [2304,32]
    float* out = (float*)d_out;                // [64,32,16]

    // ws: partial[256][BJE] (33.55 MB) + VaccBuf[BJE] (128 KB) = 33,685,504 B
    // (exactly the need256 size proven available in rounds 3-9).
    float* partial = (float*)d_ws;
    float* VaccBuf = partial + (size_t)NCF * BJE;

    void* args[6] = {(void*)&x, (void*)&W, (void*)&b0,
                     (void*)&VaccBuf, (void*)&partial, (void*)&out};
    hipLaunchCooperativeKernel((const void*)caps_fused, dim3(NCF), dim3(512),
                               args, 0, stream);
}

// Round 12
// 261.708 us; speedup vs baseline: 6.7640x; 6.7640x over previous
//
#include <hip/hip_runtime.h>

#define I_DIM 2304
#define J_DIM 32
#define D_IN  8
#define E_DIM 16
#define B_DIM 64
#define BJE   (B_DIM * J_DIM * E_DIM)  // 32768
#define NC7   256
#define CH7   (I_DIM / NC7)            // 9
#define TILEW 4096                     // floats per 16KB W tile
#define XROW  (CH7 * D_IN)             // 72 floats of x per local b

typedef const __attribute__((address_space(1))) char* gcp_t;
typedef __attribute__((address_space(3)))       char* lcp_t;

// v12 = v11 with the pass-0 poison bug fixed: FIRST pass never reads Vacc
// (vacc == 0 -> logit = b0; skips the dot product entirely). Passes 1-2 read
// Vacc, which reduce_squash WROTE during pass 0 of the same call -> no
// dependence on workspace state across calls (harness re-poison safe).
// grid = 1024: chunk = bx&255 (9 i's), qb = bx>>8 (16 b's). Same-chunk blocks
// are 256 apart -> same XCD -> share the W tile via L2. Block = 256 thr =
// 4 waves; wave wv handles b = qb*16 + wv*4 + bb (bb<4); lane jj = j,
// eh = e-half. Hot loop reads ONLY LDS (x, b0, W staged) + issues the next
// W-tile DMA (global_load_lds, source-XOR-swizzled, linear LDS dest).
template <bool FIRST>
__global__ __launch_bounds__(256, 4) void caps_pass_v12(
    const float* __restrict__ x,    // [B, I, 8]
    const float* __restrict__ W,    // [I, J, 8, 16]
    const float* __restrict__ b0,   // [I, J]
    const float* __restrict__ Vacc, // [B, J, 16] (ignored when FIRST)
    float* __restrict__ partial)    // [NC7, B, J, 16]
{
    const int tid   = threadIdx.x;
    const int wv    = __builtin_amdgcn_readfirstlane(tid >> 6);  // 0..3 (SGPR)
    const int lane  = tid & 63;
    const int jj    = lane & 31;
    const int eh    = lane >> 5;
    const int km    = jj & 15;
    const int chunk = blockIdx.x & (NC7 - 1);
    const int qb    = blockIdx.x >> 8;
    const int i0    = chunk * CH7;
    const int bloc0 = wv * 4;           // local b base (SGPR)
    const int bbase = qb * 16 + bloc0;

    __shared__ float Ws[2][TILEW];        // 32 KB, linear (swizzle, no pad)
    __shared__ float Xall[16 * XROW];     // 4.6 KB: [bl][ii][d]
    __shared__ float B0s[CH7 * J_DIM];    // 1.15 KB: [ii][j]

    auto stage = [&](int buf, int itile) {
        const char* wt = (const char*)(W + (size_t)itile * TILEW);
#pragma unroll
        for (int r = 0; r < 4; ++r) {
            const int g    = (wv * 4 + r) * 64 + lane;                  // linear dest unit
            const int srcu = (g & ~31) | ((g & 31) ^ ((g >> 5) & 15));  // swizzled src
            __builtin_amdgcn_global_load_lds(
                (gcp_t)(wt + (size_t)srcu * 16),
                (lcp_t)((char*)&Ws[buf][(wv * 4 + r) * 256]),
                16, 0, 0);
        }
    };

    // ---- prologue staging (drained by the first barrier) ----
    stage(0, i0);
    if (tid < 16 * CH7) {                       // x rows: bl = tid/9, ii = tid%9
        const int bl = tid / CH7, ii = tid - bl * CH7;
        const float* xp = x + ((size_t)(qb * 16 + bl) * I_DIM + i0 + ii) * D_IN;
        const float4 a  = *(const float4*)xp;
        const float4 b4 = *(const float4*)(xp + 4);
        float* dq = &Xall[bl * XROW + ii * 8];
        *(float4*)dq = a; *(float4*)(dq + 4) = b4;
    }
    {                                           // b0 rows (288 elems)
        B0s[tid] = b0[(i0 + (tid >> 5)) * J_DIM + (tid & 31)];
        if (tid < CH7 * J_DIM - 256)
            B0s[256 + tid] = b0[(i0 + 8) * J_DIM + tid];
    }

    float vacc[4][8];
    if constexpr (!FIRST) {
#pragma unroll
        for (int bb = 0; bb < 4; ++bb) {
            const float* vp = Vacc + ((size_t)((bbase + bb) * J_DIM + jj)) * E_DIM + eh * 8;
            const float4 v0 = *(const float4*)vp;
            const float4 v1 = *(const float4*)(vp + 4);
            vacc[bb][0]=v0.x; vacc[bb][1]=v0.y; vacc[bb][2]=v0.z; vacc[bb][3]=v0.w;
            vacc[bb][4]=v1.x; vacc[bb][5]=v1.y; vacc[bb][6]=v1.z; vacc[bb][7]=v1.w;
        }
    }

    float Sacc[4][8];
#pragma unroll
    for (int bb = 0; bb < 4; ++bb)
#pragma unroll
        for (int e = 0; e < 8; ++e) Sacc[bb][e] = 0.f;

    __syncthreads();   // tile 0 + x + b0 visible

    int cur = 0;
    for (int ii = 0; ii < CH7; ++ii) {
        if (ii + 1 < CH7) stage(cur ^ 1, i0 + ii + 1);   // DMA hides under compute

        const float* wb = &Ws[cur][0];
        const float* xr = &Xall[bloc0 * XROW + ii * 8];

        float uh[4][8];
#pragma unroll
        for (int bb = 0; bb < 4; ++bb)
#pragma unroll
            for (int e = 0; e < 8; ++e) uh[bb][e] = 0.f;

        float xq[4][4];
#pragma unroll
        for (int bb = 0; bb < 4; ++bb) {      // wave-uniform LDS broadcast reads
            const float4 t = *(const float4*)(xr + bb * XROW);
            xq[bb][0]=t.x; xq[bb][1]=t.y; xq[bb][2]=t.z; xq[bb][3]=t.w;
        }
#pragma unroll
        for (int d = 0; d < 4; ++d) {
            const int u0 = (d << 2) | (eh << 1);
            const float4 wlo = *(const float4*)&wb[jj * 128 + (((u0    ) ^ km) << 2)];
            const float4 whi = *(const float4*)&wb[jj * 128 + (((u0 | 1) ^ km) << 2)];
#pragma unroll
            for (int bb = 0; bb < 4; ++bb) {
                const float xv = xq[bb][d];
                uh[bb][0] = fmaf(xv, wlo.x, uh[bb][0]);
                uh[bb][1] = fmaf(xv, wlo.y, uh[bb][1]);
                uh[bb][2] = fmaf(xv, wlo.z, uh[bb][2]);
                uh[bb][3] = fmaf(xv, wlo.w, uh[bb][3]);
                uh[bb][4] = fmaf(xv, whi.x, uh[bb][4]);
                uh[bb][5] = fmaf(xv, whi.y, uh[bb][5]);
                uh[bb][6] = fmaf(xv, whi.z, uh[bb][6]);
                uh[bb][7] = fmaf(xv, whi.w, uh[bb][7]);
            }
        }
#pragma unroll
        for (int bb = 0; bb < 4; ++bb) {
            const float4 t = *(const float4*)(xr + bb * XROW + 4);
            xq[bb][0]=t.x; xq[bb][1]=t.y; xq[bb][2]=t.z; xq[bb][3]=t.w;
        }
#pragma unroll
        for (int d = 4; d < 8; ++d) {
            const int u0 = (d << 2) | (eh << 1);
            const float4 wlo = *(const float4*)&wb[jj * 128 + (((u0    ) ^ km) << 2)];
            const float4 whi = *(const float4*)&wb[jj * 128 + (((u0 | 1) ^ km) << 2)];
#pragma unroll
            for (int bb = 0; bb < 4; ++bb) {
                const float xv = xq[bb][d - 4];
                uh[bb][0] = fmaf(xv, wlo.x, uh[bb][0]);
                uh[bb][1] = fmaf(xv, wlo.y, uh[bb][1]);
                uh[bb][2] = fmaf(xv, wlo.z, uh[bb][2]);
                uh[bb][3] = fmaf(xv, wlo.w, uh[bb][3]);
                uh[bb][4] = fmaf(xv, whi.x, uh[bb][4]);
                uh[bb][5] = fmaf(xv, whi.y, uh[bb][5]);
                uh[bb][6] = fmaf(xv, whi.z, uh[bb][6]);
                uh[bb][7] = fmaf(xv, whi.w, uh[bb][7]);
            }
        }

        const float b0v = B0s[ii * J_DIM + jj];
#pragma unroll
        for (int bb = 0; bb < 4; ++bb) {
            float l;
            if constexpr (FIRST) {
                l = b0v;                           // vacc == 0 on pass 0
            } else {
                float l0 = 0.f, l1 = 0.f;
#pragma unroll
                for (int e = 0; e < 8; e += 2) {
                    l0 = fmaf(vacc[bb][e],     uh[bb][e],     l0);
                    l1 = fmaf(vacc[bb][e + 1], uh[bb][e + 1], l1);
                }
                float lg = l0 + l1;
                lg += __shfl_xor(lg, 32);          // other e-half
                l = b0v + lg;
            }

            // softmax over jj, no max-sub (|l| small, fp32-safe; exact-math equal)
            const float p = __expf(l);
            float s = p;
#pragma unroll
            for (int k = 16; k >= 1; k >>= 1) s += __shfl_xor(s, k);
            const float c = p * __builtin_amdgcn_rcpf(s);

#pragma unroll
            for (int e = 0; e < 8; ++e) Sacc[bb][e] = fmaf(c, uh[bb][e], Sacc[bb][e]);
        }

        __syncthreads();   // drains DMA; next tile ready; readers done with cur
        cur ^= 1;
    }

#pragma unroll
    for (int bb = 0; bb < 4; ++bb) {
        float* pp = partial + (size_t)chunk * BJE
                  + ((size_t)((bbase + bb) * J_DIM + jj)) * E_DIM + eh * 8;
        *(float4*)pp       = make_float4(Sacc[bb][0], Sacc[bb][1], Sacc[bb][2], Sacc[bb][3]);
        *(float4*)(pp + 4) = make_float4(Sacc[bb][4], Sacc[bb][5], Sacc[bb][6], Sacc[bb][7]);
    }
}

// Sum partials over chunks (8 independent accumulators), then squash.
// first_it: WRITE Vacc (creates this call's state; no memset needed);
// final_it: write out.
__global__ __launch_bounds__(256) void reduce_squash(
    const float* __restrict__ partial, float* __restrict__ Vacc,
    float* __restrict__ out, const int nc, const int first_it, const int final_it)
{
    const int t = blockIdx.x * blockDim.x + threadIdx.x;  // 0..BJE-1
    float a0=0.f,a1=0.f,a2=0.f,a3=0.f,a4=0.f,a5=0.f,a6=0.f,a7=0.f;
    for (int c = 0; c < nc; c += 8) {
        a0 += partial[(size_t)(c+0) * BJE + t];
        a1 += partial[(size_t)(c+1) * BJE + t];
        a2 += partial[(size_t)(c+2) * BJE + t];
        a3 += partial[(size_t)(c+3) * BJE + t];
        a4 += partial[(size_t)(c+4) * BJE + t];
        a5 += partial[(size_t)(c+5) * BJE + t];
        a6 += partial[(size_t)(c+6) * BJE + t];
        a7 += partial[(size_t)(c+7) * BJE + t];
    }
    const float acc = ((a0+a1)+(a2+a3)) + ((a4+a5)+(a6+a7));

    float s2 = acc * acc;
#pragma unroll
    for (int k = 8; k >= 1; k >>= 1) s2 += __shfl_xor(s2, k);  // reduce over e
    const float scale = s2 / (1.f + s2) * rsqrtf(s2 + 1e-7f);
    const float v = scale * acc;
    if (final_it)      out[t] = v;
    else if (first_it) Vacc[t] = v;
    else               Vacc[t] += v;
}

extern "C" void kernel_launch(void* const* d_in, const int* in_sizes, int n_in,
                              void* d_out, int out_size, void* d_ws, size_t ws_size,
                              hipStream_t stream) {
    const float* x  = (const float*)d_in[0];   // [64,2304,8]
    const float* W  = (const float*)d_in[1];   // [2304,32,8,16]
    const float* b0 = (const float*)d_in[2];   // [2304,32]
    float* out = (float*)d_out;                // [64,32,16]

    // ws layout: partial[256][BJE] (33.5 MB) + Vacc[BJE] (128 KB); ws proven
    // >= 33.7 MB in rounds 3-10. Pass 0 never reads Vacc; reduce_squash writes
    // it fresh each call -> safe under harness ws poisoning.
    float* partial = (float*)d_ws;
    float* Vacc    = partial + (size_t)NC7 * BJE;

    caps_pass_v12<true><<<NC7 * 4, 256, 0, stream>>>(x, W, b0, Vacc, partial);
    reduce_squash<<<BJE / 256, 256, 0, stream>>>(partial, Vacc, out, NC7, 1, 0);

    caps_pass_v12<false><<<NC7 * 4, 256, 0, stream>>>(x, W, b0, Vacc, partial);
    reduce_squash<<<BJE / 256, 256, 0, stream>>>(partial, Vacc, out, NC7, 0, 0);

    caps_pass_v12<false><<<NC7 * 4, 256, 0, stream>>>(x, W, b0, Vacc, partial);
    reduce_squash<<<BJE / 256, 256, 0, stream>>>(partial, Vacc, out, NC7, 0, 1);
}

// Round 13
// 166.123 us; speedup vs baseline: 10.6559x; 1.5754x over previous
//
#include <hip/hip_runtime.h>

#define I_DIM 2304
#define J_DIM 32
#define D_IN  8
#define E_DIM 16
#define B_DIM 64
#define BJE   (B_DIM * J_DIM * E_DIM)  // 32768
#define NC7   256
#define CH7   (I_DIM / NC7)            // 9
#define TILEW 4096                     // floats per 16KB W tile
#define XROW  (CH7 * D_IN)             // 72 floats of x per local b

typedef const __attribute__((address_space(1))) char* gcp_t;
typedef __attribute__((address_space(3)))       char* lcp_t;

// v13 = v12 with __launch_bounds__(256,3) restored — the ONLY config hipcc
// compiles spill-free for this kernel (84 VGPR, proven r7; (256,4)->64 VGPR
// spills, r12; 512/1024-thr blocks halve the cap and spill, r8/r9).
// FIRST template: pass 0 never reads Vacc (poison-safe, r11 lesson).
// grid = 1024: chunk = bx&255 (9 i's), qb = bx>>8 (16 b's). Same-chunk blocks
// are 256 apart -> same XCD -> share the W tile via L2. Block = 256 thr =
// 4 waves; wave wv handles b = qb*16 + wv*4 + bb (bb<4); lane jj = j,
// eh = e-half. Hot loop reads ONLY LDS (x, b0, W staged) + issues the next
// W-tile DMA (global_load_lds, source-XOR-swizzled, linear LDS dest).
template <bool FIRST>
__global__ __launch_bounds__(256, 3) void caps_pass_v13(
    const float* __restrict__ x,    // [B, I, 8]
    const float* __restrict__ W,    // [I, J, 8, 16]
    const float* __restrict__ b0,   // [I, J]
    const float* __restrict__ Vacc, // [B, J, 16] (ignored when FIRST)
    float* __restrict__ partial)    // [NC7, B, J, 16]
{
    const int tid   = threadIdx.x;
    const int wv    = __builtin_amdgcn_readfirstlane(tid >> 6);  // 0..3 (SGPR)
    const int lane  = tid & 63;
    const int jj    = lane & 31;
    const int eh    = lane >> 5;
    const int km    = jj & 15;
    const int chunk = blockIdx.x & (NC7 - 1);
    const int qb    = blockIdx.x >> 8;
    const int i0    = chunk * CH7;
    const int bloc0 = wv * 4;           // local b base (SGPR)
    const int bbase = qb * 16 + bloc0;

    __shared__ float Ws[2][TILEW];        // 32 KB, linear (swizzle, no pad)
    __shared__ float Xall[16 * XROW];     // 4.6 KB: [bl][ii][d]
    __shared__ float B0s[CH7 * J_DIM];    // 1.15 KB: [ii][j]

    auto stage = [&](int buf, int itile) {
        const char* wt = (const char*)(W + (size_t)itile * TILEW);
#pragma unroll
        for (int r = 0; r < 4; ++r) {
            const int g    = (wv * 4 + r) * 64 + lane;                  // linear dest unit
            const int srcu = (g & ~31) | ((g & 31) ^ ((g >> 5) & 15));  // swizzled src
            __builtin_amdgcn_global_load_lds(
                (gcp_t)(wt + (size_t)srcu * 16),
                (lcp_t)((char*)&Ws[buf][(wv * 4 + r) * 256]),
                16, 0, 0);
        }
    };

    // ---- prologue staging (drained by the first barrier) ----
    stage(0, i0);
    if (tid < 16 * CH7) {                       // x rows: bl = tid/9, ii = tid%9
        const int bl = tid / CH7, ii = tid - bl * CH7;
        const float* xp = x + ((size_t)(qb * 16 + bl) * I_DIM + i0 + ii) * D_IN;
        const float4 a  = *(const float4*)xp;
        const float4 b4 = *(const float4*)(xp + 4);
        float* dq = &Xall[bl * XROW + ii * 8];
        *(float4*)dq = a; *(float4*)(dq + 4) = b4;
    }
    {                                           // b0 rows (288 elems)
        B0s[tid] = b0[(i0 + (tid >> 5)) * J_DIM + (tid & 31)];
        if (tid < CH7 * J_DIM - 256)
            B0s[256 + tid] = b0[(i0 + 8) * J_DIM + tid];
    }

    float vacc[4][8];
    if constexpr (!FIRST) {
#pragma unroll
        for (int bb = 0; bb < 4; ++bb) {
            const float* vp = Vacc + ((size_t)((bbase + bb) * J_DIM + jj)) * E_DIM + eh * 8;
            const float4 v0 = *(const float4*)vp;
            const float4 v1 = *(const float4*)(vp + 4);
            vacc[bb][0]=v0.x; vacc[bb][1]=v0.y; vacc[bb][2]=v0.z; vacc[bb][3]=v0.w;
            vacc[bb][4]=v1.x; vacc[bb][5]=v1.y; vacc[bb][6]=v1.z; vacc[bb][7]=v1.w;
        }
    }

    float Sacc[4][8];
#pragma unroll
    for (int bb = 0; bb < 4; ++bb)
#pragma unroll
        for (int e = 0; e < 8; ++e) Sacc[bb][e] = 0.f;

    __syncthreads();   // tile 0 + x + b0 visible

    int cur = 0;
    for (int ii = 0; ii < CH7; ++ii) {
        if (ii + 1 < CH7) stage(cur ^ 1, i0 + ii + 1);   // DMA hides under compute

        const float* wb = &Ws[cur][0];
        const float* xr = &Xall[bloc0 * XROW + ii * 8];

        float uh[4][8];
#pragma unroll
        for (int bb = 0; bb < 4; ++bb)
#pragma unroll
            for (int e = 0; e < 8; ++e) uh[bb][e] = 0.f;

        float xq[4][4];
#pragma unroll
        for (int bb = 0; bb < 4; ++bb) {      // wave-uniform LDS broadcast reads
            const float4 t = *(const float4*)(xr + bb * XROW);
            xq[bb][0]=t.x; xq[bb][1]=t.y; xq[bb][2]=t.z; xq[bb][3]=t.w;
        }
#pragma unroll
        for (int d = 0; d < 4; ++d) {
            const int u0 = (d << 2) | (eh << 1);
            const float4 wlo = *(const float4*)&wb[jj * 128 + (((u0    ) ^ km) << 2)];
            const float4 whi = *(const float4*)&wb[jj * 128 + (((u0 | 1) ^ km) << 2)];
#pragma unroll
            for (int bb = 0; bb < 4; ++bb) {
                const float xv = xq[bb][d];
                uh[bb][0] = fmaf(xv, wlo.x, uh[bb][0]);
                uh[bb][1] = fmaf(xv, wlo.y, uh[bb][1]);
                uh[bb][2] = fmaf(xv, wlo.z, uh[bb][2]);
                uh[bb][3] = fmaf(xv, wlo.w, uh[bb][3]);
                uh[bb][4] = fmaf(xv, whi.x, uh[bb][4]);
                uh[bb][5] = fmaf(xv, whi.y, uh[bb][5]);
                uh[bb][6] = fmaf(xv, whi.z, uh[bb][6]);
                uh[bb][7] = fmaf(xv, whi.w, uh[bb][7]);
            }
        }
#pragma unroll
        for (int bb = 0; bb < 4; ++bb) {
            const float4 t = *(const float4*)(xr + bb * XROW + 4);
            xq[bb][0]=t.x; xq[bb][1]=t.y; xq[bb][2]=t.z; xq[bb][3]=t.w;
        }
#pragma unroll
        for (int d = 4; d < 8; ++d) {
            const int u0 = (d << 2) | (eh << 1);
            const float4 wlo = *(const float4*)&wb[jj * 128 + (((u0    ) ^ km) << 2)];
            const float4 whi = *(const float4*)&wb[jj * 128 + (((u0 | 1) ^ km) << 2)];
#pragma unroll
            for (int bb = 0; bb < 4; ++bb) {
                const float xv = xq[bb][d - 4];
                uh[bb][0] = fmaf(xv, wlo.x, uh[bb][0]);
                uh[bb][1] = fmaf(xv, wlo.y, uh[bb][1]);
                uh[bb][2] = fmaf(xv, wlo.z, uh[bb][2]);
                uh[bb][3] = fmaf(xv, wlo.w, uh[bb][3]);
                uh[bb][4] = fmaf(xv, whi.x, uh[bb][4]);
                uh[bb][5] = fmaf(xv, whi.y, uh[bb][5]);
                uh[bb][6] = fmaf(xv, whi.z, uh[bb][6]);
                uh[bb][7] = fmaf(xv, whi.w, uh[bb][7]);
            }
        }

        const float b0v = B0s[ii * J_DIM + jj];
#pragma unroll
        for (int bb = 0; bb < 4; ++bb) {
            float l;
            if constexpr (FIRST) {
                l = b0v;                           // vacc == 0 on pass 0
            } else {
                float l0 = 0.f, l1 = 0.f;
#pragma unroll
                for (int e = 0; e < 8; e += 2) {
                    l0 = fmaf(vacc[bb][e],     uh[bb][e],     l0);
                    l1 = fmaf(vacc[bb][e + 1], uh[bb][e + 1], l1);
                }
                float lg = l0 + l1;
                lg += __shfl_xor(lg, 32);          // other e-half
                l = b0v + lg;
            }

            // softmax over jj, no max-sub (|l| small, fp32-safe; exact-math equal)
            const float p = __expf(l);
            float s = p;
#pragma unroll
            for (int k = 16; k >= 1; k >>= 1) s += __shfl_xor(s, k);
            const float c = p * __builtin_amdgcn_rcpf(s);

#pragma unroll
            for (int e = 0; e < 8; ++e) Sacc[bb][e] = fmaf(c, uh[bb][e], Sacc[bb][e]);
        }

        __syncthreads();   // drains DMA; next tile ready; readers done with cur
        cur ^= 1;
    }

#pragma unroll
    for (int bb = 0; bb < 4; ++bb) {
        float* pp = partial + (size_t)chunk * BJE
                  + ((size_t)((bbase + bb) * J_DIM + jj)) * E_DIM + eh * 8;
        *(float4*)pp       = make_float4(Sacc[bb][0], Sacc[bb][1], Sacc[bb][2], Sacc[bb][3]);
        *(float4*)(pp + 4) = make_float4(Sacc[bb][4], Sacc[bb][5], Sacc[bb][6], Sacc[bb][7]);
    }
}

// Sum partials over chunks (8 independent accumulators), then squash.
// first_it: WRITE Vacc (creates this call's state; no memset needed);
// final_it: write out.
__global__ __launch_bounds__(256) void reduce_squash(
    const float* __restrict__ partial, float* __restrict__ Vacc,
    float* __restrict__ out, const int nc, const int first_it, const int final_it)
{
    const int t = blockIdx.x * blockDim.x + threadIdx.x;  // 0..BJE-1
    float a0=0.f,a1=0.f,a2=0.f,a3=0.f,a4=0.f,a5=0.f,a6=0.f,a7=0.f;
    for (int c = 0; c < nc; c += 8) {
        a0 += partial[(size_t)(c+0) * BJE + t];
        a1 += partial[(size_t)(c+1) * BJE + t];
        a2 += partial[(size_t)(c+2) * BJE + t];
        a3 += partial[(size_t)(c+3) * BJE + t];
        a4 += partial[(size_t)(c+4) * BJE + t];
        a5 += partial[(size_t)(c+5) * BJE + t];
        a6 += partial[(size_t)(c+6) * BJE + t];
        a7 += partial[(size_t)(c+7) * BJE + t];
    }
    const float acc = ((a0+a1)+(a2+a3)) + ((a4+a5)+(a6+a7));

    float s2 = acc * acc;
#pragma unroll
    for (int k = 8; k >= 1; k >>= 1) s2 += __shfl_xor(s2, k);  // reduce over e
    const float scale = s2 / (1.f + s2) * rsqrtf(s2 + 1e-7f);
    const float v = scale * acc;
    if (final_it)      out[t] = v;
    else if (first_it) Vacc[t] = v;
    else               Vacc[t] += v;
}

extern "C" void kernel_launch(void* const* d_in, const int* in_sizes, int n_in,
                              void* d_out, int out_size, void* d_ws, size_t ws_size,
                              hipStream_t stream) {
    const float* x  = (const float*)d_in[0];   // [64,2304,8]
    const float* W  = (const float*)d_in[1];   // [2304,32,8,16]
    const float* b0 = (const float*)d_in[2];   // [2304,32]
    float* out = (float*)d_out;                // [64,32,16]

    // ws layout: partial[256][BJE] (33.5 MB) + Vacc[BJE] (128 KB); ws proven
    // >= 33.7 MB in rounds 3-12. Pass 0 never reads Vacc; reduce_squash writes
    // it fresh each call -> safe under harness ws poisoning.
    float* partial = (float*)d_ws;
    float* Vacc    = partial + (size_t)NC7 * BJE;

    caps_pass_v13<true><<<NC7 * 4, 256, 0, stream>>>(x, W, b0, Vacc, partial);
    reduce_squash<<<BJE / 256, 256, 0, stream>>>(partial, Vacc, out, NC7, 1, 0);

    caps_pass_v13<false><<<NC7 * 4, 256, 0, stream>>>(x, W, b0, Vacc, partial);
    reduce_squash<<<BJE / 256, 256, 0, stream>>>(partial, Vacc, out, NC7, 0, 0);

    caps_pass_v13<false><<<NC7 * 4, 256, 0, stream>>>(x, W, b0, Vacc, partial);
    reduce_squash<<<BJE / 256, 256, 0, stream>>>(partial, Vacc, out, NC7, 0, 1);
}